// Round 4
// baseline (1006.949 us; speedup 1.0000x reference)
//
#include <hip/hip_runtime.h>
#include <cstdint>
#include <cstddef>
#include <cmath>

// ClipLoss fused: loss = mean_i( 0.5*(lse_row_i + lse_col_i) - diag_i )
// logits = SCALE * img @ txt^T. Stats kept in exp2 domain:
// bf16 img copy is pre-scaled by CF = SCALE*log2(e), so MFMA accumulators are
// already exp2-domain logits u; lse_nat = ln2 * (m + log2(s)).
//
// R4: K-loop loads BOTH MFMA fragments directly global->VGPR (16 B contiguous
// per lane), no LDS staging, no barriers in the loop. LDS only for epilogue.

#define N_ROWS 16384
#define DIM    512
#define NB     128
#define SCALE  14.285714285714286f
#define CF     20.609929155556625f   // SCALE * log2(e)
#define LN2F   0.6931471805599453f
#define SP     36                    // part[] row stride in floats (144 B)

typedef __attribute__((ext_vector_type(8))) short   short8;
typedef __attribute__((ext_vector_type(4))) float   floatx4;

#if __has_builtin(__builtin_amdgcn_exp2f)
#define EXP2(x) __builtin_amdgcn_exp2f(x)
#else
#define EXP2(x) exp2f(x)
#endif

// ---------------------------------------------------------------- helpers ---
__device__ __forceinline__ unsigned short f2bf(float f) {
    union { float f; unsigned int u; } c; c.f = f;
    unsigned int u = c.u;
    unsigned int r = (u + 0x7fffu + ((u >> 16) & 1u)) >> 16;  // RNE
    return (unsigned short)r;
}

__device__ __forceinline__ void lse_merge2(float& m, float& s, float om, float os) {
    float nm = fmaxf(m, om);
    s = s * EXP2(m - nm) + os * EXP2(om - nm);
    m = nm;
}

// --------------------------------------------------- cvt + diag (fused) -----
__global__ void cvt_diag_kernel(const float* __restrict__ a, const float* __restrict__ b,
                                unsigned short* __restrict__ Ab, unsigned short* __restrict__ Bb,
                                float* __restrict__ diag) {
    const int w = threadIdx.x >> 6, lane = threadIdx.x & 63;
#pragma unroll
    for (int it = 0; it < 2; ++it) {
        const int row = blockIdx.x * 8 + w * 2 + it;
        const float4* ar = (const float4*)(a + (size_t)row * DIM);
        const float4* br = (const float4*)(b + (size_t)row * DIM);
        ushort4* ao = (ushort4*)(Ab + (size_t)row * DIM);
        ushort4* bo = (ushort4*)(Bb + (size_t)row * DIM);
        float dot = 0.f;
#pragma unroll
        for (int j = lane; j < DIM / 4; j += 64) {
            float4 x = ar[j], y = br[j];
            dot += x.x * y.x + x.y * y.y + x.z * y.z + x.w * y.w;
            ushort4 ox, oy;
            ox.x = f2bf(CF * x.x); ox.y = f2bf(CF * x.y);
            ox.z = f2bf(CF * x.z); ox.w = f2bf(CF * x.w);
            oy.x = f2bf(y.x); oy.y = f2bf(y.y);
            oy.z = f2bf(y.z); oy.w = f2bf(y.w);
            ao[j] = ox; bo[j] = oy;
        }
        for (int mask = 32; mask; mask >>= 1) dot += __shfl_xor(dot, mask);
        if (lane == 0) diag[row] = SCALE * dot;
    }
}

// --------------------------------------------------- fused GEMM + LSE -------
__global__ __launch_bounds__(256, 3)
void gemm_lse_kernel(const unsigned short* __restrict__ A,
                     const unsigned short* __restrict__ B,
                     float* __restrict__ row_m, float* __restrict__ row_s,
                     float* __restrict__ col_m, float* __restrict__ col_s) {
    __shared__ __align__(16) float part[128 * SP];   // epilogue only (18 KB)

    const int t = threadIdx.x;
    const int bid = blockIdx.x;

    // XCD-aware swizzle: each XCD owns a 16-row A band (L2-resident), sweeps bc
    const int xcd   = bid & 7;
    const int local = bid >> 3;
    const int br    = xcd * 16 + (local & 15);
    const int bc    = local >> 4;

    const int lane = t & 63;
    const int w    = t >> 6;
    const int quad = lane >> 4;
    const int l15  = lane & 15;
    const int wrow = w >> 1;
    const int wcol = w & 1;

    floatx4 acc[4][4];
#pragma unroll
    for (int i = 0; i < 4; ++i)
#pragma unroll
        for (int j = 0; j < 4; ++j)
            acc[i][j] = (floatx4){0.f, 0.f, 0.f, 0.f};

    // direct-global fragment pointers: lane reads A[row][k..k+7], 16 B aligned
    const unsigned short* pa = A + (size_t)(br * 128 + wrow * 64 + l15) * DIM + quad * 8;
    const unsigned short* pb = B + (size_t)(bc * 128 + wcol * 64 + l15) * DIM + quad * 8;

    short8 af[2][4], bf[2][4];
#pragma unroll
    for (int i = 0; i < 4; ++i) {
        af[0][i] = *(const short8*)(pa + i * 16 * DIM);
        bf[0][i] = *(const short8*)(pb + i * 16 * DIM);
    }

#pragma unroll
    for (int kk = 0; kk < 16; ++kk) {
        const int cur = kk & 1, nxt = cur ^ 1;
        if (kk < 15) {
#pragma unroll
            for (int i = 0; i < 4; ++i) {
                af[nxt][i] = *(const short8*)(pa + (kk + 1) * 32 + i * 16 * DIM);
                bf[nxt][i] = *(const short8*)(pb + (kk + 1) * 32 + i * 16 * DIM);
            }
        }
#pragma unroll
        for (int mi = 0; mi < 4; ++mi)
#pragma unroll
            for (int ni = 0; ni < 4; ++ni)
                acc[mi][ni] = __builtin_amdgcn_mfma_f32_16x16x32_bf16(
                    af[cur][mi], bf[cur][ni], acc[mi][ni], 0, 0, 0);
    }

    // ---- epilogue. C/D layout (16x16): col = lane&15, row = quad*4 + reg. ----
    // lane holds rows lrow = wrow*64+mi*16+quad*4+r, cols wcol*64+ni*16+l15.

    // phase A1: row partial max (over ni) -> part[lrow][wcol*16+l15]
#pragma unroll
    for (int mi = 0; mi < 4; ++mi)
#pragma unroll
        for (int r = 0; r < 4; ++r) {
            float pm = fmaxf(fmaxf(acc[mi][0][r], acc[mi][1][r]),
                             fmaxf(acc[mi][2][r], acc[mi][3][r]));
            int lrow = wrow * 64 + mi * 16 + quad * 4 + r;
            part[lrow * SP + wcol * 16 + l15] = pm;
        }

    // phase A2: col stats (shfl over quads) -> part[cl][32..35]
#pragma unroll
    for (int ni = 0; ni < 4; ++ni) {
        float m = acc[0][ni][0];
#pragma unroll
        for (int mi = 0; mi < 4; ++mi)
#pragma unroll
            for (int r = 0; r < 4; ++r)
                m = fmaxf(m, acc[mi][ni][r]);
        m = fmaxf(m, __shfl_xor(m, 16));
        m = fmaxf(m, __shfl_xor(m, 32));
        float s = 0.f;
#pragma unroll
        for (int mi = 0; mi < 4; ++mi)
#pragma unroll
            for (int r = 0; r < 4; ++r)
                s += EXP2(acc[mi][ni][r] - m);
        s += __shfl_xor(s, 16);
        s += __shfl_xor(s, 32);
        if (quad == 0) {
            int cl = wcol * 64 + ni * 16 + l15;
            part[cl * SP + 32 + wrow] = m;   // 32,33
            part[cl * SP + 34 + wrow] = s;   // 34,35
        }
    }
    __syncthreads();

    if (t < 128) {
        // finish cols: merge wrow halves, store
        float m = part[t * SP + 32], s = part[t * SP + 34];
        lse_merge2(m, s, part[t * SP + 33], part[t * SP + 35]);
        col_m[(size_t)br * N_ROWS + bc * 128 + t] = m;
        col_s[(size_t)br * N_ROWS + bc * 128 + t] = s;
        // row max over 32 partials (8 x float4, conflict-free: stride 144 B)
        const float4* p4 = (const float4*)&part[t * SP];
        float4 v = p4[0];
#pragma unroll
        for (int j = 1; j < 8; ++j) {
            float4 u = p4[j];
            v.x = fmaxf(v.x, u.x); v.y = fmaxf(v.y, u.y);
            v.z = fmaxf(v.z, u.z); v.w = fmaxf(v.w, u.w);
        }
        part[t * SP + 32] = fmaxf(fmaxf(v.x, v.y), fmaxf(v.z, v.w));
    }
    __syncthreads();

    // phase B: row partial sums with broadcast max
#pragma unroll
    for (int mi = 0; mi < 4; ++mi)
#pragma unroll
        for (int r = 0; r < 4; ++r) {
            int lrow = wrow * 64 + mi * 16 + quad * 4 + r;
            float m = part[lrow * SP + 32];
            float s = EXP2(acc[mi][0][r] - m) + EXP2(acc[mi][1][r] - m)
                    + EXP2(acc[mi][2][r] - m) + EXP2(acc[mi][3][r] - m);
            part[lrow * SP + wcol * 16 + l15] = s;
        }
    __syncthreads();

    if (t < 128) {
        const float4* p4 = (const float4*)&part[t * SP];
        float4 v = p4[0];
#pragma unroll
        for (int j = 1; j < 8; ++j) {
            float4 u = p4[j];
            v.x += u.x; v.y += u.y; v.z += u.z; v.w += u.w;
        }
        float s = (v.x + v.y) + (v.z + v.w);
        float m = part[t * SP + 32];
        row_m[(size_t)bc * N_ROWS + br * 128 + t] = m;
        row_s[(size_t)bc * N_ROWS + br * 128 + t] = s;
    }
}

// --------------------------------------------------------- final reduce -----
__global__ void reduce_kernel(const float* __restrict__ row_m, const float* __restrict__ row_s,
                              const float* __restrict__ col_m, const float* __restrict__ col_s,
                              const float* __restrict__ diag, float* __restrict__ out) {
    const int w = threadIdx.x >> 6, lane = threadIdx.x & 63;
    const int row = blockIdx.x * 64 + lane;
    const size_t jt0 = (size_t)w * 32;

    float m = row_m[jt0 * N_ROWS + row];
    float s = row_s[jt0 * N_ROWS + row];
    for (int k = 1; k < 32; ++k)
        lse_merge2(m, s, row_m[(jt0 + k) * N_ROWS + row], row_s[(jt0 + k) * N_ROWS + row]);
    float mc = col_m[jt0 * N_ROWS + row];
    float sc = col_s[jt0 * N_ROWS + row];
    for (int k = 1; k < 32; ++k)
        lse_merge2(mc, sc, col_m[(jt0 + k) * N_ROWS + row], col_s[(jt0 + k) * N_ROWS + row]);

    __shared__ float sm[4][64], ss[4][64], tm[4][64], ts[4][64];
    sm[w][lane] = m;  ss[w][lane] = s;
    tm[w][lane] = mc; ts[w][lane] = sc;
    __syncthreads();

    if (w == 0) {
#pragma unroll
        for (int h = 1; h < 4; ++h) lse_merge2(m, s, sm[h][lane], ss[h][lane]);
        float lse_r = m + log2f(s);
#pragma unroll
        for (int h = 1; h < 4; ++h) lse_merge2(mc, sc, tm[h][lane], ts[h][lane]);
        float lse_c = mc + log2f(sc);
        float contrib = 0.5f * LN2F * (lse_r + lse_c) - diag[row];
        for (int mask = 32; mask; mask >>= 1) contrib += __shfl_xor(contrib, mask);
        if (lane == 0) atomicAdd(out, contrib * (1.0f / N_ROWS));
    }
}

// -------------------------------------------------------------- launch ------
extern "C" void kernel_launch(void* const* d_in, const int* in_sizes, int n_in,
                              void* d_out, int out_size, void* d_ws, size_t ws_size,
                              hipStream_t stream) {
    const float* img = (const float*)d_in[0];
    const float* txt = (const float*)d_in[1];
    char* ws = (char*)d_ws;

    const size_t MB = 1024 * 1024;
    unsigned short* Ab = (unsigned short*)(ws);                 // 16 MB bf16 CF*img
    unsigned short* Bb = (unsigned short*)(ws + 16 * MB);       // 16 MB bf16 txt
    float* row_m = (float*)(ws + 32 * MB);                      // 8 MB
    float* row_s = (float*)(ws + 40 * MB);                      // 8 MB
    float* col_m = (float*)(ws + 48 * MB);                      // 8 MB
    float* col_s = (float*)(ws + 56 * MB);                      // 8 MB
    float* diag  = (float*)(ws + 64 * MB);                      // 64 KB
    float* out   = (float*)d_out;

    hipMemsetAsync(d_out, 0, sizeof(float), stream);
    cvt_diag_kernel<<<N_ROWS / 8, 256, 0, stream>>>(img, txt, Ab, Bb, diag);
    gemm_lse_kernel<<<NB * NB, 256, 0, stream>>>(Ab, Bb, row_m, row_s, col_m, col_s);
    reduce_kernel<<<N_ROWS / 64, 256, 0, stream>>>(row_m, row_s, col_m, col_s, diag, out);
}

// Round 5
// 607.309 us; speedup vs baseline: 1.6580x; 1.6580x over previous
//
#include <hip/hip_runtime.h>
#include <cstdint>
#include <cstddef>
#include <cmath>

// ClipLoss fused: loss = mean_i( 0.5*(lse_row_i + lse_col_i) - diag_i )
// logits = SCALE * img @ txt^T. Stats kept in exp2 domain:
// bf16 img copy is pre-scaled by CF = SCALE*log2(e), so MFMA accumulators are
// already exp2-domain logits u; lse_nat = ln2 * (m + log2(s)).
//
// R5: R3 structure (LDS-staged m97-style K-loop) with a k-chunked LDS layout:
// slot(quad,row) = quad*128 + row, 16 B/slot. Fragment ds_read_b128 hits 8
// consecutive slots per 8-lane group -> all 32 banks -> conflict-free.

#define N_ROWS 16384
#define DIM    512
#define NB     128
#define SCALE  14.285714285714286f
#define CF     20.609929155556625f   // SCALE * log2(e)
#define LN2F   0.6931471805599453f
#define SP     36                    // part[] row stride in floats (144 B)

typedef __attribute__((ext_vector_type(8))) short   short8;
typedef __attribute__((ext_vector_type(4))) float   floatx4;

#if __has_builtin(__builtin_amdgcn_exp2f)
#define EXP2(x) __builtin_amdgcn_exp2f(x)
#else
#define EXP2(x) exp2f(x)
#endif

// ---------------------------------------------------------------- helpers ---
__device__ __forceinline__ unsigned short f2bf(float f) {
    union { float f; unsigned int u; } c; c.f = f;
    unsigned int u = c.u;
    unsigned int r = (u + 0x7fffu + ((u >> 16) & 1u)) >> 16;  // RNE
    return (unsigned short)r;
}

__device__ __forceinline__ void async_load16(const void* g, void* l) {
    __builtin_amdgcn_global_load_lds(
        (__attribute__((address_space(1))) void*)(void*)(g),
        (__attribute__((address_space(3))) void*)(l), 16, 0, 0);
}

__device__ __forceinline__ void lse_merge2(float& m, float& s, float om, float os) {
    float nm = fmaxf(m, om);
    s = s * EXP2(m - nm) + os * EXP2(om - nm);
    m = nm;
}

// --------------------------------------------------- cvt + diag (fused) -----
__global__ void cvt_diag_kernel(const float* __restrict__ a, const float* __restrict__ b,
                                unsigned short* __restrict__ Ab, unsigned short* __restrict__ Bb,
                                float* __restrict__ diag) {
    const int w = threadIdx.x >> 6, lane = threadIdx.x & 63;
#pragma unroll
    for (int it = 0; it < 2; ++it) {
        const int row = blockIdx.x * 8 + w * 2 + it;
        const float4* ar = (const float4*)(a + (size_t)row * DIM);
        const float4* br = (const float4*)(b + (size_t)row * DIM);
        ushort4* ao = (ushort4*)(Ab + (size_t)row * DIM);
        ushort4* bo = (ushort4*)(Bb + (size_t)row * DIM);
        float dot = 0.f;
#pragma unroll
        for (int j = lane; j < DIM / 4; j += 64) {
            float4 x = ar[j], y = br[j];
            dot += x.x * y.x + x.y * y.y + x.z * y.z + x.w * y.w;
            ushort4 ox, oy;
            ox.x = f2bf(CF * x.x); ox.y = f2bf(CF * x.y);
            ox.z = f2bf(CF * x.z); ox.w = f2bf(CF * x.w);
            oy.x = f2bf(y.x); oy.y = f2bf(y.y);
            oy.z = f2bf(y.z); oy.w = f2bf(y.w);
            ao[j] = ox; bo[j] = oy;
        }
        for (int mask = 32; mask; mask >>= 1) dot += __shfl_xor(dot, mask);
        if (lane == 0) diag[row] = SCALE * dot;
    }
}

// --------------------------------------------------- fused GEMM + LSE -------
__global__ void gemm_lse_kernel(const unsigned short* __restrict__ A,
                                const unsigned short* __restrict__ B,
                                float* __restrict__ row_m, float* __restrict__ row_s,
                                float* __restrict__ col_m, float* __restrict__ col_s) {
    // staging (16 KB) overlaid with epilogue partial matrix (18 KB)
    __shared__ __align__(16) unsigned char smem[128 * SP * 4];
    unsigned short* sA = (unsigned short*)smem;            // k-chunked, 8 KB
    unsigned short* sB = (unsigned short*)(smem + 8192);   // k-chunked, 8 KB
    float* part = (float*)smem;                            // [128][SP]

    const int t = threadIdx.x;
    const int bid = blockIdx.x;

    // XCD-aware swizzle: each XCD owns a 16-row A band (L2-resident), sweeps bc
    const int xcd   = bid & 7;
    const int local = bid >> 3;
    const int br    = xcd * 16 + (local & 15);
    const int bc    = local >> 4;

    const int lane = t & 63;
    const int w    = t >> 6;
    const int quad = lane >> 4;
    const int l15  = lane & 15;
    const int wrow = w >> 1;
    const int wcol = w & 1;

    floatx4 acc[4][4];
#pragma unroll
    for (int i = 0; i < 4; ++i)
#pragma unroll
        for (int j = 0; j < 4; ++j)
            acc[i][j] = (floatx4){0.f, 0.f, 0.f, 0.f};

    // staging: waves 0,1 -> A quads {0,1},{2,3}; waves 2,3 -> B likewise.
    // chunk c: q = qbase + (c>>1), rh = c&1. One instruction = 64 rows x 16 B,
    // LDS dest contiguous (slot q*128 + rh*64 + lane), global is a row-gather.
    const int isB   = w >> 1;
    const int qbase = (w & 1) * 2;
    const unsigned short* gsrc = isB
        ? B + (size_t)(bc * 128) * DIM
        : A + (size_t)(br * 128) * DIM;
    unsigned short* lbase = isB ? sB : sA;

    const unsigned short* gq[4];
    unsigned short* lq[4];
#pragma unroll
    for (int c = 0; c < 4; ++c) {
        const int q  = qbase + (c >> 1);
        const int rh = c & 1;
        gq[c] = gsrc + (size_t)(rh * 64 + lane) * DIM + q * 8;
        lq[c] = lbase + (q * 128 + rh * 64) * 8;
    }

    for (int k0 = 0; k0 < DIM; k0 += 32) {
        async_load16(gq[0] + k0, lq[0]);
        async_load16(gq[1] + k0, lq[1]);
        async_load16(gq[2] + k0, lq[2]);
        async_load16(gq[3] + k0, lq[3]);
        __builtin_amdgcn_s_waitcnt(0);
        __syncthreads();

        short8 av[4], bv[4];
#pragma unroll
        for (int mi = 0; mi < 4; ++mi)
            av[mi] = *(const short8*)&sA[(quad * 128 + wrow * 64 + mi * 16 + l15) * 8];
#pragma unroll
        for (int ni = 0; ni < 4; ++ni)
            bv[ni] = *(const short8*)&sB[(quad * 128 + wcol * 64 + ni * 16 + l15) * 8];
#pragma unroll
        for (int mi = 0; mi < 4; ++mi)
#pragma unroll
            for (int ni = 0; ni < 4; ++ni)
                acc[mi][ni] = __builtin_amdgcn_mfma_f32_16x16x32_bf16(
                    av[mi], bv[ni], acc[mi][ni], 0, 0, 0);
        __syncthreads();
    }

    // ---- epilogue. C/D layout (16x16): col = lane&15, row = quad*4 + reg. ----
    // lane holds rows lrow = wrow*64+mi*16+quad*4+r, cols wcol*64+ni*16+l15.

    // phase A1: row partial max (over ni) -> part[lrow][wcol*16+l15]
#pragma unroll
    for (int mi = 0; mi < 4; ++mi)
#pragma unroll
        for (int r = 0; r < 4; ++r) {
            float pm = fmaxf(fmaxf(acc[mi][0][r], acc[mi][1][r]),
                             fmaxf(acc[mi][2][r], acc[mi][3][r]));
            int lrow = wrow * 64 + mi * 16 + quad * 4 + r;
            part[lrow * SP + wcol * 16 + l15] = pm;
        }

    // phase A2: col stats (shfl over quads) -> part[cl][32..35]
#pragma unroll
    for (int ni = 0; ni < 4; ++ni) {
        float m = acc[0][ni][0];
#pragma unroll
        for (int mi = 0; mi < 4; ++mi)
#pragma unroll
            for (int r = 0; r < 4; ++r)
                m = fmaxf(m, acc[mi][ni][r]);
        m = fmaxf(m, __shfl_xor(m, 16));
        m = fmaxf(m, __shfl_xor(m, 32));
        float s = 0.f;
#pragma unroll
        for (int mi = 0; mi < 4; ++mi)
#pragma unroll
            for (int r = 0; r < 4; ++r)
                s += EXP2(acc[mi][ni][r] - m);
        s += __shfl_xor(s, 16);
        s += __shfl_xor(s, 32);
        if (quad == 0) {
            int cl = wcol * 64 + ni * 16 + l15;
            part[cl * SP + 32 + wrow] = m;   // 32,33
            part[cl * SP + 34 + wrow] = s;   // 34,35
        }
    }
    __syncthreads();

    if (t < 128) {
        // finish cols: merge wrow halves, store
        float m = part[t * SP + 32], s = part[t * SP + 34];
        lse_merge2(m, s, part[t * SP + 33], part[t * SP + 35]);
        col_m[(size_t)br * N_ROWS + bc * 128 + t] = m;
        col_s[(size_t)br * N_ROWS + bc * 128 + t] = s;
        // row max over 32 partials (8 x float4, conflict-free: stride 144 B)
        const float4* p4 = (const float4*)&part[t * SP];
        float4 v = p4[0];
#pragma unroll
        for (int j = 1; j < 8; ++j) {
            float4 u = p4[j];
            v.x = fmaxf(v.x, u.x); v.y = fmaxf(v.y, u.y);
            v.z = fmaxf(v.z, u.z); v.w = fmaxf(v.w, u.w);
        }
        part[t * SP + 32] = fmaxf(fmaxf(v.x, v.y), fmaxf(v.z, v.w));
    }
    __syncthreads();

    // phase B: row partial sums with broadcast max
#pragma unroll
    for (int mi = 0; mi < 4; ++mi)
#pragma unroll
        for (int r = 0; r < 4; ++r) {
            int lrow = wrow * 64 + mi * 16 + quad * 4 + r;
            float m = part[lrow * SP + 32];
            float s = EXP2(acc[mi][0][r] - m) + EXP2(acc[mi][1][r] - m)
                    + EXP2(acc[mi][2][r] - m) + EXP2(acc[mi][3][r] - m);
            part[lrow * SP + wcol * 16 + l15] = s;
        }
    __syncthreads();

    if (t < 128) {
        const float4* p4 = (const float4*)&part[t * SP];
        float4 v = p4[0];
#pragma unroll
        for (int j = 1; j < 8; ++j) {
            float4 u = p4[j];
            v.x += u.x; v.y += u.y; v.z += u.z; v.w += u.w;
        }
        float s = (v.x + v.y) + (v.z + v.w);
        float m = part[t * SP + 32];
        row_m[(size_t)bc * N_ROWS + br * 128 + t] = m;
        row_s[(size_t)bc * N_ROWS + br * 128 + t] = s;
    }
}

// --------------------------------------------------------- final reduce -----
__global__ void reduce_kernel(const float* __restrict__ row_m, const float* __restrict__ row_s,
                              const float* __restrict__ col_m, const float* __restrict__ col_s,
                              const float* __restrict__ diag, float* __restrict__ out) {
    const int w = threadIdx.x >> 6, lane = threadIdx.x & 63;
    const int row = blockIdx.x * 64 + lane;
    const size_t jt0 = (size_t)w * 32;

    float m = row_m[jt0 * N_ROWS + row];
    float s = row_s[jt0 * N_ROWS + row];
    for (int k = 1; k < 32; ++k)
        lse_merge2(m, s, row_m[(jt0 + k) * N_ROWS + row], row_s[(jt0 + k) * N_ROWS + row]);
    float mc = col_m[jt0 * N_ROWS + row];
    float sc = col_s[jt0 * N_ROWS + row];
    for (int k = 1; k < 32; ++k)
        lse_merge2(mc, sc, col_m[(jt0 + k) * N_ROWS + row], col_s[(jt0 + k) * N_ROWS + row]);

    __shared__ float sm[4][64], ss[4][64], tm[4][64], ts[4][64];
    sm[w][lane] = m;  ss[w][lane] = s;
    tm[w][lane] = mc; ts[w][lane] = sc;
    __syncthreads();

    if (w == 0) {
#pragma unroll
        for (int h = 1; h < 4; ++h) lse_merge2(m, s, sm[h][lane], ss[h][lane]);
        float lse_r = m + log2f(s);
#pragma unroll
        for (int h = 1; h < 4; ++h) lse_merge2(mc, sc, tm[h][lane], ts[h][lane]);
        float lse_c = mc + log2f(sc);
        float contrib = 0.5f * LN2F * (lse_r + lse_c) - diag[row];
        for (int mask = 32; mask; mask >>= 1) contrib += __shfl_xor(contrib, mask);
        if (lane == 0) atomicAdd(out, contrib * (1.0f / N_ROWS));
    }
}

// -------------------------------------------------------------- launch ------
extern "C" void kernel_launch(void* const* d_in, const int* in_sizes, int n_in,
                              void* d_out, int out_size, void* d_ws, size_t ws_size,
                              hipStream_t stream) {
    const float* img = (const float*)d_in[0];
    const float* txt = (const float*)d_in[1];
    char* ws = (char*)d_ws;

    const size_t MB = 1024 * 1024;
    unsigned short* Ab = (unsigned short*)(ws);                 // 16 MB bf16 CF*img
    unsigned short* Bb = (unsigned short*)(ws + 16 * MB);       // 16 MB bf16 txt
    float* row_m = (float*)(ws + 32 * MB);                      // 8 MB
    float* row_s = (float*)(ws + 40 * MB);                      // 8 MB
    float* col_m = (float*)(ws + 48 * MB);                      // 8 MB
    float* col_s = (float*)(ws + 56 * MB);                      // 8 MB
    float* diag  = (float*)(ws + 64 * MB);                      // 64 KB
    float* out   = (float*)d_out;

    hipMemsetAsync(d_out, 0, sizeof(float), stream);
    cvt_diag_kernel<<<N_ROWS / 8, 256, 0, stream>>>(img, txt, Ab, Bb, diag);
    gemm_lse_kernel<<<NB * NB, 256, 0, stream>>>(Ab, Bb, row_m, row_s, col_m, col_s);
    reduce_kernel<<<N_ROWS / 64, 256, 0, stream>>>(row_m, row_s, col_m, col_s, diag, out);
}

// Round 6
// 394.526 us; speedup vs baseline: 2.5523x; 1.5393x over previous
//
#include <hip/hip_runtime.h>
#include <cstdint>
#include <cstddef>
#include <cmath>

// ClipLoss fused: loss = mean_i( 0.5*(lse_row_i + lse_col_i) - diag_i )
// logits = SCALE * img @ txt^T. Stats kept in exp2 domain:
// bf16 img copy is pre-scaled by CF = SCALE*log2(e).
//
// R6: bf16 copies stored PRE-SWIZZLED: A'[kb][q][row][8 bf16]
// (kb = k-block of 32, q = 8-elem k-granule). Staging global_load_lds then
// reads 1 KB contiguous per instruction AND lands in the k-chunked LDS
// layout slot(q,row)=q*128+row -> conflict-free ds_read_b128 fragments.

#define N_ROWS 16384
#define DIM    512
#define NB     128
#define SCALE  14.285714285714286f
#define CF     20.609929155556625f   // SCALE * log2(e)
#define LN2F   0.6931471805599453f
#define SP     36                    // part[] row stride in floats (144 B)
#define KBSTR  ((size_t)4 * N_ROWS * 8)   // shorts per kb step in A'/B'

typedef __attribute__((ext_vector_type(8))) short          short8;
typedef __attribute__((ext_vector_type(8))) unsigned short ushort8;
typedef __attribute__((ext_vector_type(4))) float          floatx4;

#if __has_builtin(__builtin_amdgcn_exp2f)
#define EXP2(x) __builtin_amdgcn_exp2f(x)
#else
#define EXP2(x) exp2f(x)
#endif

// ---------------------------------------------------------------- helpers ---
__device__ __forceinline__ unsigned short f2bf(float f) {
    union { float f; unsigned int u; } c; c.f = f;
    unsigned int u = c.u;
    unsigned int r = (u + 0x7fffu + ((u >> 16) & 1u)) >> 16;  // RNE
    return (unsigned short)r;
}

__device__ __forceinline__ void async_load16(const void* g, void* l) {
    __builtin_amdgcn_global_load_lds(
        (__attribute__((address_space(1))) void*)(void*)(g),
        (__attribute__((address_space(3))) void*)(l), 16, 0, 0);
}

__device__ __forceinline__ void lse_merge2(float& m, float& s, float om, float os) {
    float nm = fmaxf(m, om);
    s = s * EXP2(m - nm) + os * EXP2(om - nm);
    m = nm;
}

// --------------------------------------------- cvt + swizzle + diag ---------
// Block = 256 threads handles 64 rows. Wave w owns granule q=w of every kb:
// reads img/txt [row][kb*32+w*8 .. +8] (32 B gather), writes A'/B' 1 KB
// coalesced per (kb, tensor), accumulates the exact fp32 diagonal dot.
__global__ void cvt_diag_kernel(const float* __restrict__ a, const float* __restrict__ b,
                                unsigned short* __restrict__ Ab, unsigned short* __restrict__ Bb,
                                float* __restrict__ diag) {
    const int w = threadIdx.x >> 6, lane = threadIdx.x & 63;
    const int row = blockIdx.x * 64 + lane;
    float dot = 0.f;
#pragma unroll
    for (int kb = 0; kb < 16; ++kb) {
        const int col = kb * 32 + w * 8;
        const float4* ai = (const float4*)(a + (size_t)row * DIM + col);
        const float4* bi = (const float4*)(b + (size_t)row * DIM + col);
        float4 x0 = ai[0], x1 = ai[1];
        float4 y0 = bi[0], y1 = bi[1];
        dot += x0.x * y0.x + x0.y * y0.y + x0.z * y0.z + x0.w * y0.w
             + x1.x * y1.x + x1.y * y1.y + x1.z * y1.z + x1.w * y1.w;
        ushort8 oa, ob;
        oa[0] = f2bf(CF * x0.x); oa[1] = f2bf(CF * x0.y);
        oa[2] = f2bf(CF * x0.z); oa[3] = f2bf(CF * x0.w);
        oa[4] = f2bf(CF * x1.x); oa[5] = f2bf(CF * x1.y);
        oa[6] = f2bf(CF * x1.z); oa[7] = f2bf(CF * x1.w);
        ob[0] = f2bf(y0.x); ob[1] = f2bf(y0.y);
        ob[2] = f2bf(y0.z); ob[3] = f2bf(y0.w);
        ob[4] = f2bf(y1.x); ob[5] = f2bf(y1.y);
        ob[6] = f2bf(y1.z); ob[7] = f2bf(y1.w);
        const size_t o = ((size_t)(kb * 4 + w) * N_ROWS + row) * 8;
        *(ushort8*)(Ab + o) = oa;
        *(ushort8*)(Bb + o) = ob;
    }
    __shared__ float pd[4][64];
    pd[w][lane] = dot;
    __syncthreads();
    if (w == 0)
        diag[row] = SCALE * (pd[0][lane] + pd[1][lane] + pd[2][lane] + pd[3][lane]);
}

// --------------------------------------------------- fused GEMM + LSE -------
__global__ void gemm_lse_kernel(const unsigned short* __restrict__ A,
                                const unsigned short* __restrict__ B,
                                float* __restrict__ row_m, float* __restrict__ row_s,
                                float* __restrict__ col_m, float* __restrict__ col_s) {
    // staging (16 KB) overlaid with epilogue partial matrix (18 KB)
    __shared__ __align__(16) unsigned char smem[128 * SP * 4];
    unsigned short* sA = (unsigned short*)smem;            // k-chunked, 8 KB
    unsigned short* sB = (unsigned short*)(smem + 8192);   // k-chunked, 8 KB
    float* part = (float*)smem;                            // [128][SP]

    const int t = threadIdx.x;
    const int bid = blockIdx.x;

    // XCD-aware swizzle: each XCD owns a 16-row A band (L2-resident), sweeps bc
    const int xcd   = bid & 7;
    const int local = bid >> 3;
    const int br    = xcd * 16 + (local & 15);
    const int bc    = local >> 4;

    const int lane = t & 63;
    const int w    = t >> 6;
    const int quad = lane >> 4;
    const int l15  = lane & 15;
    const int wrow = w >> 1;
    const int wcol = w & 1;

    floatx4 acc[4][4];
#pragma unroll
    for (int i = 0; i < 4; ++i)
#pragma unroll
        for (int j = 0; j < 4; ++j)
            acc[i][j] = (floatx4){0.f, 0.f, 0.f, 0.f};

    // staging: waves 0,1 -> A granules {0,1},{2,3}; waves 2,3 -> B likewise.
    // chunk c: q = qbase + (c>>1), rh = c&1. One instruction stages 64
    // consecutive swizzled rows x 16 B = 1 KB contiguous global -> contiguous LDS.
    const int isB   = w >> 1;
    const int qbase = (w & 1) * 2;
    const unsigned short* gsrc = isB ? B : A;
    const int rbase = (isB ? bc : br) * 128;
    unsigned short* lbase = isB ? sB : sA;

    const unsigned short* gq[4];
    unsigned short* lq[4];
#pragma unroll
    for (int c = 0; c < 4; ++c) {
        const int q  = qbase + (c >> 1);
        const int rh = c & 1;
        gq[c] = gsrc + ((size_t)q * N_ROWS + rbase + rh * 64 + lane) * 8;
        lq[c] = lbase + (q * 128 + rh * 64) * 8;
    }

    for (int kb = 0; kb < 16; ++kb) {
        const size_t ko = (size_t)kb * KBSTR;
        async_load16(gq[0] + ko, lq[0]);
        async_load16(gq[1] + ko, lq[1]);
        async_load16(gq[2] + ko, lq[2]);
        async_load16(gq[3] + ko, lq[3]);
        __builtin_amdgcn_s_waitcnt(0);
        __syncthreads();

        short8 av[4], bv[4];
#pragma unroll
        for (int mi = 0; mi < 4; ++mi)
            av[mi] = *(const short8*)&sA[(quad * 128 + wrow * 64 + mi * 16 + l15) * 8];
#pragma unroll
        for (int ni = 0; ni < 4; ++ni)
            bv[ni] = *(const short8*)&sB[(quad * 128 + wcol * 64 + ni * 16 + l15) * 8];
#pragma unroll
        for (int mi = 0; mi < 4; ++mi)
#pragma unroll
            for (int ni = 0; ni < 4; ++ni)
                acc[mi][ni] = __builtin_amdgcn_mfma_f32_16x16x32_bf16(
                    av[mi], bv[ni], acc[mi][ni], 0, 0, 0);
        __syncthreads();
    }

    // ---- epilogue. C/D layout (16x16): col = lane&15, row = quad*4 + reg. ----
    // lane holds rows lrow = wrow*64+mi*16+quad*4+r, cols wcol*64+ni*16+l15.

    // phase A1: row partial max (over ni) -> part[lrow][wcol*16+l15]
#pragma unroll
    for (int mi = 0; mi < 4; ++mi)
#pragma unroll
        for (int r = 0; r < 4; ++r) {
            float pm = fmaxf(fmaxf(acc[mi][0][r], acc[mi][1][r]),
                             fmaxf(acc[mi][2][r], acc[mi][3][r]));
            int lrow = wrow * 64 + mi * 16 + quad * 4 + r;
            part[lrow * SP + wcol * 16 + l15] = pm;
        }

    // phase A2: col stats (shfl over quads) -> part[cl][32..35]
#pragma unroll
    for (int ni = 0; ni < 4; ++ni) {
        float m = acc[0][ni][0];
#pragma unroll
        for (int mi = 0; mi < 4; ++mi)
#pragma unroll
            for (int r = 0; r < 4; ++r)
                m = fmaxf(m, acc[mi][ni][r]);
        m = fmaxf(m, __shfl_xor(m, 16));
        m = fmaxf(m, __shfl_xor(m, 32));
        float s = 0.f;
#pragma unroll
        for (int mi = 0; mi < 4; ++mi)
#pragma unroll
            for (int r = 0; r < 4; ++r)
                s += EXP2(acc[mi][ni][r] - m);
        s += __shfl_xor(s, 16);
        s += __shfl_xor(s, 32);
        if (quad == 0) {
            int cl = wcol * 64 + ni * 16 + l15;
            part[cl * SP + 32 + wrow] = m;   // 32,33
            part[cl * SP + 34 + wrow] = s;   // 34,35
        }
    }
    __syncthreads();

    if (t < 128) {
        // finish cols: merge wrow halves, store
        float m = part[t * SP + 32], s = part[t * SP + 34];
        lse_merge2(m, s, part[t * SP + 33], part[t * SP + 35]);
        col_m[(size_t)br * N_ROWS + bc * 128 + t] = m;
        col_s[(size_t)br * N_ROWS + bc * 128 + t] = s;
        // row max over 32 partials (8 x float4, conflict-free: stride 144 B)
        const float4* p4 = (const float4*)&part[t * SP];
        float4 v = p4[0];
#pragma unroll
        for (int j = 1; j < 8; ++j) {
            float4 u = p4[j];
            v.x = fmaxf(v.x, u.x); v.y = fmaxf(v.y, u.y);
            v.z = fmaxf(v.z, u.z); v.w = fmaxf(v.w, u.w);
        }
        part[t * SP + 32] = fmaxf(fmaxf(v.x, v.y), fmaxf(v.z, v.w));
    }
    __syncthreads();

    // phase B: row partial sums with broadcast max
#pragma unroll
    for (int mi = 0; mi < 4; ++mi)
#pragma unroll
        for (int r = 0; r < 4; ++r) {
            int lrow = wrow * 64 + mi * 16 + quad * 4 + r;
            float m = part[lrow * SP + 32];
            float s = EXP2(acc[mi][0][r] - m) + EXP2(acc[mi][1][r] - m)
                    + EXP2(acc[mi][2][r] - m) + EXP2(acc[mi][3][r] - m);
            part[lrow * SP + wcol * 16 + l15] = s;
        }
    __syncthreads();

    if (t < 128) {
        const float4* p4 = (const float4*)&part[t * SP];
        float4 v = p4[0];
#pragma unroll
        for (int j = 1; j < 8; ++j) {
            float4 u = p4[j];
            v.x += u.x; v.y += u.y; v.z += u.z; v.w += u.w;
        }
        float s = (v.x + v.y) + (v.z + v.w);
        float m = part[t * SP + 32];
        row_m[(size_t)bc * N_ROWS + br * 128 + t] = m;
        row_s[(size_t)bc * N_ROWS + br * 128 + t] = s;
    }
}

// --------------------------------------------------------- final reduce -----
__global__ void reduce_kernel(const float* __restrict__ row_m, const float* __restrict__ row_s,
                              const float* __restrict__ col_m, const float* __restrict__ col_s,
                              const float* __restrict__ diag, float* __restrict__ out) {
    const int w = threadIdx.x >> 6, lane = threadIdx.x & 63;
    const int row = blockIdx.x * 64 + lane;
    const size_t jt0 = (size_t)w * 32;

    float m = row_m[jt0 * N_ROWS + row];
    float s = row_s[jt0 * N_ROWS + row];
    for (int k = 1; k < 32; ++k)
        lse_merge2(m, s, row_m[(jt0 + k) * N_ROWS + row], row_s[(jt0 + k) * N_ROWS + row]);
    float mc = col_m[jt0 * N_ROWS + row];
    float sc = col_s[jt0 * N_ROWS + row];
    for (int k = 1; k < 32; ++k)
        lse_merge2(mc, sc, col_m[(jt0 + k) * N_ROWS + row], col_s[(jt0 + k) * N_ROWS + row]);

    __shared__ float sm[4][64], ss[4][64], tm[4][64], ts[4][64];
    sm[w][lane] = m;  ss[w][lane] = s;
    tm[w][lane] = mc; ts[w][lane] = sc;
    __syncthreads();

    if (w == 0) {
#pragma unroll
        for (int h = 1; h < 4; ++h) lse_merge2(m, s, sm[h][lane], ss[h][lane]);
        float lse_r = m + log2f(s);
#pragma unroll
        for (int h = 1; h < 4; ++h) lse_merge2(mc, sc, tm[h][lane], ts[h][lane]);
        float lse_c = mc + log2f(sc);
        float contrib = 0.5f * LN2F * (lse_r + lse_c) - diag[row];
        for (int mask = 32; mask; mask >>= 1) contrib += __shfl_xor(contrib, mask);
        if (lane == 0) atomicAdd(out, contrib * (1.0f / N_ROWS));
    }
}

// -------------------------------------------------------------- launch ------
extern "C" void kernel_launch(void* const* d_in, const int* in_sizes, int n_in,
                              void* d_out, int out_size, void* d_ws, size_t ws_size,
                              hipStream_t stream) {
    const float* img = (const float*)d_in[0];
    const float* txt = (const float*)d_in[1];
    char* ws = (char*)d_ws;

    const size_t MB = 1024 * 1024;
    unsigned short* Ab = (unsigned short*)(ws);                 // 16 MB swizzled bf16 CF*img
    unsigned short* Bb = (unsigned short*)(ws + 16 * MB);       // 16 MB swizzled bf16 txt
    float* row_m = (float*)(ws + 32 * MB);                      // 8 MB
    float* row_s = (float*)(ws + 40 * MB);                      // 8 MB
    float* col_m = (float*)(ws + 48 * MB);                      // 8 MB
    float* col_s = (float*)(ws + 56 * MB);                      // 8 MB
    float* diag  = (float*)(ws + 64 * MB);                      // 64 KB
    float* out   = (float*)d_out;

    hipMemsetAsync(d_out, 0, sizeof(float), stream);
    cvt_diag_kernel<<<N_ROWS / 64, 256, 0, stream>>>(img, txt, Ab, Bb, diag);
    gemm_lse_kernel<<<NB * NB, 256, 0, stream>>>(Ab, Bb, row_m, row_s, col_m, col_s);
    reduce_kernel<<<N_ROWS / 64, 256, 0, stream>>>(row_m, row_s, col_m, col_s, diag, out);
}

// Round 7
// 329.306 us; speedup vs baseline: 3.0578x; 1.1981x over previous
//
#include <hip/hip_runtime.h>
#include <cstdint>
#include <cstddef>
#include <cmath>

// ClipLoss fused: loss = mean_i( 0.5*(lse_row_i + lse_col_i) - diag_i )
// logits = SCALE * img @ txt^T. Stats in exp2 domain: fp8 img copy is
// pre-scaled by CF = SCALE*log2(e); lse_nat = ln2 * (m + log2(s)).
//
// R7: MX-scaled FP8 GEMM. A'/B' stored as e4m3 pre-swizzled
// [kb][g][row][32 fp8] (kb = k-block of 128, g = 32-elem k-granule).
// K-loop: 4 iterations of BK=128, 16x16x128 f8f6f4 MFMA with unit E8M0
// scales (127 -> 2^0). Staging: 1 KB contiguous global -> k-chunked LDS
// slot(g,row)=(g*128+row)*32B -> conflict-free 2x ds_read_b128 fragments.

#define N_ROWS 16384
#define DIM    512
#define NB     128
#define SCALE  14.285714285714286f
#define CF     20.609929155556625f   // SCALE * log2(e)
#define LN2F   0.6931471805599453f
#define SP     36                    // part[] row stride in floats (144 B)

typedef __attribute__((ext_vector_type(8))) int   int8v;
typedef __attribute__((ext_vector_type(4))) int   int4v;
typedef __attribute__((ext_vector_type(4))) float floatx4;

#if __has_builtin(__builtin_amdgcn_exp2f)
#define EXP2(x) __builtin_amdgcn_exp2f(x)
#else
#define EXP2(x) exp2f(x)
#endif

// ---------------------------------------------------------------- helpers ---
__device__ __forceinline__ void async_load16(const void* g, void* l) {
    __builtin_amdgcn_global_load_lds(
        (__attribute__((address_space(1))) void*)(void*)(g),
        (__attribute__((address_space(3))) void*)(l), 16, 0, 0);
}

__device__ __forceinline__ void lse_merge2(float& m, float& s, float om, float os) {
    float nm = fmaxf(m, om);
    s = s * EXP2(m - nm) + os * EXP2(om - nm);
    m = nm;
}

// pack 4 floats -> 4 e4m3 bytes in one i32 (RNE, OCP on gfx950)
__device__ __forceinline__ int pk_fp8x4(float a, float b, float c, float d) {
    int u = __builtin_amdgcn_cvt_pk_fp8_f32(a, b, 0, false);
    u = __builtin_amdgcn_cvt_pk_fp8_f32(c, d, u, true);
    return u;
}

// --------------------------------------------- cvt + swizzle + diag ---------
// Block = 256 threads = 16 rows x 16 granules. Thread (rl, g16) converts
// img/txt[row][g16*32 .. +31] to fp8 (img scaled by CF) and writes the
// 32-B granule to A'/B' at ((g16*N + row)*32); also partial diag dot.
__global__ void cvt_diag_kernel(const float* __restrict__ a, const float* __restrict__ b,
                                unsigned char* __restrict__ A8, unsigned char* __restrict__ B8,
                                float* __restrict__ diag) {
    const int t  = threadIdx.x;
    const int rl = t & 15, g16 = t >> 4;
    const int row = blockIdx.x * 16 + rl;
    const float4* ai = (const float4*)(a + (size_t)row * DIM + g16 * 32);
    const float4* bi = (const float4*)(b + (size_t)row * DIM + g16 * 32);
    float dot = 0.f;
    int wa[8], wb[8];
#pragma unroll
    for (int j = 0; j < 4; ++j) {
        float4 x0 = ai[2 * j], x1 = ai[2 * j + 1];
        float4 y0 = bi[2 * j], y1 = bi[2 * j + 1];
        dot += x0.x * y0.x + x0.y * y0.y + x0.z * y0.z + x0.w * y0.w
             + x1.x * y1.x + x1.y * y1.y + x1.z * y1.z + x1.w * y1.w;
        wa[2 * j]     = pk_fp8x4(CF * x0.x, CF * x0.y, CF * x0.z, CF * x0.w);
        wa[2 * j + 1] = pk_fp8x4(CF * x1.x, CF * x1.y, CF * x1.z, CF * x1.w);
        wb[2 * j]     = pk_fp8x4(y0.x, y0.y, y0.z, y0.w);
        wb[2 * j + 1] = pk_fp8x4(y1.x, y1.y, y1.z, y1.w);
    }
    const size_t o = ((size_t)g16 * N_ROWS + row) * 32;
    *(int4v*)(A8 + o)      = (int4v){wa[0], wa[1], wa[2], wa[3]};
    *(int4v*)(A8 + o + 16) = (int4v){wa[4], wa[5], wa[6], wa[7]};
    *(int4v*)(B8 + o)      = (int4v){wb[0], wb[1], wb[2], wb[3]};
    *(int4v*)(B8 + o + 16) = (int4v){wb[4], wb[5], wb[6], wb[7]};

    __shared__ float pd[16][17];
    pd[rl][g16] = dot;
    __syncthreads();
    if (t < 16) {
        float s = 0.f;
#pragma unroll
        for (int j = 0; j < 16; ++j) s += pd[t][j];
        diag[blockIdx.x * 16 + t] = SCALE * s;
    }
}

// --------------------------------------------------- fused GEMM + LSE -------
__global__ void gemm_lse_kernel(const unsigned char* __restrict__ A8,
                                const unsigned char* __restrict__ B8,
                                float* __restrict__ row_m, float* __restrict__ row_s,
                                float* __restrict__ col_m, float* __restrict__ col_s) {
    __shared__ __align__(16) unsigned char smem[32768];
    unsigned char* sA = smem;            // 16 KB: slot(g,row) = (g*128+row)*32
    unsigned char* sB = smem + 16384;    // 16 KB
    float* part = (float*)smem;          // [128][SP] = 18432 B overlay

    const int t = threadIdx.x;
    const int bid = blockIdx.x;

    // XCD-aware swizzle: each XCD owns a 16-row A band (L2-resident), sweeps bc
    const int xcd   = bid & 7;
    const int local = bid >> 3;
    const int br    = xcd * 16 + (local & 15);
    const int bc    = local >> 4;

    const int lane = t & 63;
    const int w    = t >> 6;
    const int quad = lane >> 4;
    const int l15  = lane & 15;
    const int wrow = w >> 1;
    const int wcol = w & 1;

    floatx4 acc[4][4];
#pragma unroll
    for (int i = 0; i < 4; ++i)
#pragma unroll
        for (int j = 0; j < 4; ++j)
            acc[i][j] = (floatx4){0.f, 0.f, 0.f, 0.f};

    // staging: waves 0,1 -> A granule-planes {0,1},{2,3}; waves 2,3 -> B.
    // piece c: g = gbase + (c>>2), i = c&3; one instr = 1 KB contiguous.
    const int isB   = w >> 1;
    const int gbase = (w & 1) * 2;
    const unsigned char* gsrc = isB ? B8 : A8;
    const int rbase = (isB ? bc : br) * 128;
    unsigned char* lbase = isB ? sB : sA;

    const unsigned char* gp[8];
    unsigned char* lp[8];
#pragma unroll
    for (int c = 0; c < 8; ++c) {
        const int g = gbase + (c >> 2), i = c & 3;
        gp[c] = gsrc + ((size_t)g * N_ROWS + rbase) * 32 + i * 1024 + lane * 16;
        lp[c] = lbase + g * 4096 + i * 1024;
    }
    const size_t kbstr = (size_t)4 * N_ROWS * 32;   // bytes per kb step

    for (int kb = 0; kb < 4; ++kb) {
        const size_t ko = (size_t)kb * kbstr;
#pragma unroll
        for (int c = 0; c < 8; ++c) async_load16(gp[c] + ko, lp[c]);
        __builtin_amdgcn_s_waitcnt(0);
        __syncthreads();

        int8v av[4], bv[4];
#pragma unroll
        for (int mi = 0; mi < 4; ++mi) {
            const unsigned char* p = sA + (quad * 128 + wrow * 64 + mi * 16 + l15) * 32;
            int4v lo = *(const int4v*)p;
            int4v hi = *(const int4v*)(p + 16);
            av[mi] = (int8v){lo[0], lo[1], lo[2], lo[3], hi[0], hi[1], hi[2], hi[3]};
        }
#pragma unroll
        for (int ni = 0; ni < 4; ++ni) {
            const unsigned char* p = sB + (quad * 128 + wcol * 64 + ni * 16 + l15) * 32;
            int4v lo = *(const int4v*)p;
            int4v hi = *(const int4v*)(p + 16);
            bv[ni] = (int8v){lo[0], lo[1], lo[2], lo[3], hi[0], hi[1], hi[2], hi[3]};
        }
#pragma unroll
        for (int mi = 0; mi < 4; ++mi)
#pragma unroll
            for (int ni = 0; ni < 4; ++ni)
                acc[mi][ni] = __builtin_amdgcn_mfma_scale_f32_16x16x128_f8f6f4(
                    av[mi], bv[ni], acc[mi][ni], 0, 0, 0, 127, 0, 127);
        __syncthreads();
    }

    // ---- epilogue. C/D layout (16x16): col = lane&15, row = quad*4 + reg. ----
    // lane holds rows lrow = wrow*64+mi*16+quad*4+r, cols wcol*64+ni*16+l15.

    // phase A1: row partial max (over ni) -> part[lrow][wcol*16+l15]
#pragma unroll
    for (int mi = 0; mi < 4; ++mi)
#pragma unroll
        for (int r = 0; r < 4; ++r) {
            float pm = fmaxf(fmaxf(acc[mi][0][r], acc[mi][1][r]),
                             fmaxf(acc[mi][2][r], acc[mi][3][r]));
            int lrow = wrow * 64 + mi * 16 + quad * 4 + r;
            part[lrow * SP + wcol * 16 + l15] = pm;
        }

    // phase A2: col stats (shfl over quads) -> part[cl][32..35]
#pragma unroll
    for (int ni = 0; ni < 4; ++ni) {
        float m = acc[0][ni][0];
#pragma unroll
        for (int mi = 0; mi < 4; ++mi)
#pragma unroll
            for (int r = 0; r < 4; ++r)
                m = fmaxf(m, acc[mi][ni][r]);
        m = fmaxf(m, __shfl_xor(m, 16));
        m = fmaxf(m, __shfl_xor(m, 32));
        float s = 0.f;
#pragma unroll
        for (int mi = 0; mi < 4; ++mi)
#pragma unroll
            for (int r = 0; r < 4; ++r)
                s += EXP2(acc[mi][ni][r] - m);
        s += __shfl_xor(s, 16);
        s += __shfl_xor(s, 32);
        if (quad == 0) {
            int cl = wcol * 64 + ni * 16 + l15;
            part[cl * SP + 32 + wrow] = m;   // 32,33
            part[cl * SP + 34 + wrow] = s;   // 34,35
        }
    }
    __syncthreads();

    if (t < 128) {
        // finish cols: merge wrow halves, store
        float m = part[t * SP + 32], s = part[t * SP + 34];
        lse_merge2(m, s, part[t * SP + 33], part[t * SP + 35]);
        col_m[(size_t)br * N_ROWS + bc * 128 + t] = m;
        col_s[(size_t)br * N_ROWS + bc * 128 + t] = s;
        // row max over 32 partials (8 x float4, stride 144 B)
        const float4* p4 = (const float4*)&part[t * SP];
        float4 v = p4[0];
#pragma unroll
        for (int j = 1; j < 8; ++j) {
            float4 u = p4[j];
            v.x = fmaxf(v.x, u.x); v.y = fmaxf(v.y, u.y);
            v.z = fmaxf(v.z, u.z); v.w = fmaxf(v.w, u.w);
        }
        part[t * SP + 32] = fmaxf(fmaxf(v.x, v.y), fmaxf(v.z, v.w));
    }
    __syncthreads();

    // phase B: row partial sums with broadcast max
#pragma unroll
    for (int mi = 0; mi < 4; ++mi)
#pragma unroll
        for (int r = 0; r < 4; ++r) {
            int lrow = wrow * 64 + mi * 16 + quad * 4 + r;
            float m = part[lrow * SP + 32];
            float s = EXP2(acc[mi][0][r] - m) + EXP2(acc[mi][1][r] - m)
                    + EXP2(acc[mi][2][r] - m) + EXP2(acc[mi][3][r] - m);
            part[lrow * SP + wcol * 16 + l15] = s;
        }
    __syncthreads();

    if (t < 128) {
        const float4* p4 = (const float4*)&part[t * SP];
        float4 v = p4[0];
#pragma unroll
        for (int j = 1; j < 8; ++j) {
            float4 u = p4[j];
            v.x += u.x; v.y += u.y; v.z += u.z; v.w += u.w;
        }
        float s = (v.x + v.y) + (v.z + v.w);
        float m = part[t * SP + 32];
        row_m[(size_t)bc * N_ROWS + br * 128 + t] = m;
        row_s[(size_t)bc * N_ROWS + br * 128 + t] = s;
    }
}

// --------------------------------------------------------- final reduce -----
__global__ void reduce_kernel(const float* __restrict__ row_m, const float* __restrict__ row_s,
                              const float* __restrict__ col_m, const float* __restrict__ col_s,
                              const float* __restrict__ diag, float* __restrict__ out) {
    const int w = threadIdx.x >> 6, lane = threadIdx.x & 63;
    const int row = blockIdx.x * 64 + lane;
    const size_t jt0 = (size_t)w * 32;

    float m = row_m[jt0 * N_ROWS + row];
    float s = row_s[jt0 * N_ROWS + row];
    for (int k = 1; k < 32; ++k)
        lse_merge2(m, s, row_m[(jt0 + k) * N_ROWS + row], row_s[(jt0 + k) * N_ROWS + row]);
    float mc = col_m[jt0 * N_ROWS + row];
    float sc = col_s[jt0 * N_ROWS + row];
    for (int k = 1; k < 32; ++k)
        lse_merge2(mc, sc, col_m[(jt0 + k) * N_ROWS + row], col_s[(jt0 + k) * N_ROWS + row]);

    __shared__ float sm[4][64], ss[4][64], tm[4][64], ts[4][64];
    sm[w][lane] = m;  ss[w][lane] = s;
    tm[w][lane] = mc; ts[w][lane] = sc;
    __syncthreads();

    if (w == 0) {
#pragma unroll
        for (int h = 1; h < 4; ++h) lse_merge2(m, s, sm[h][lane], ss[h][lane]);
        float lse_r = m + log2f(s);
#pragma unroll
        for (int h = 1; h < 4; ++h) lse_merge2(mc, sc, tm[h][lane], ts[h][lane]);
        float lse_c = mc + log2f(sc);
        float contrib = 0.5f * LN2F * (lse_r + lse_c) - diag[row];
        for (int mask = 32; mask; mask >>= 1) contrib += __shfl_xor(contrib, mask);
        if (lane == 0) atomicAdd(out, contrib * (1.0f / N_ROWS));
    }
}

// -------------------------------------------------------------- launch ------
extern "C" void kernel_launch(void* const* d_in, const int* in_sizes, int n_in,
                              void* d_out, int out_size, void* d_ws, size_t ws_size,
                              hipStream_t stream) {
    const float* img = (const float*)d_in[0];
    const float* txt = (const float*)d_in[1];
    char* ws = (char*)d_ws;

    const size_t MB = 1024 * 1024;
    unsigned char* A8 = (unsigned char*)(ws);                   // 8 MB fp8 swizzled CF*img
    unsigned char* B8 = (unsigned char*)(ws + 8 * MB);          // 8 MB fp8 swizzled txt
    float* row_m = (float*)(ws + 16 * MB);                      // 8 MB
    float* row_s = (float*)(ws + 24 * MB);                      // 8 MB
    float* col_m = (float*)(ws + 32 * MB);                      // 8 MB
    float* col_s = (float*)(ws + 40 * MB);                      // 8 MB
    float* diag  = (float*)(ws + 48 * MB);                      // 64 KB
    float* out   = (float*)d_out;

    hipMemsetAsync(d_out, 0, sizeof(float), stream);
    cvt_diag_kernel<<<N_ROWS / 16, 256, 0, stream>>>(img, txt, A8, B8, diag);
    gemm_lse_kernel<<<NB * NB, 256, 0, stream>>>(A8, B8, row_m, row_s, col_m, col_s);
    reduce_kernel<<<N_ROWS / 64, 256, 0, stream>>>(row_m, row_s, col_m, col_s, diag, out);
}